// Round 1
// baseline (3226.298 us; speedup 1.0000x reference)
//
#include <hip/hip_runtime.h>

typedef _Float16 fp16_t;
typedef _Float16 v8h __attribute__((ext_vector_type(8)));
typedef float    v4f __attribute__((ext_vector_type(4)));

#define RELAX_LR 0.3f

// async global->LDS, 16B per lane. LDS dest = wave-uniform base + lane*16.
__device__ __forceinline__ void async_cp16(const void* g, void* l) {
    __builtin_amdgcn_global_load_lds(
        (const __attribute__((address_space(1))) void*)g,
        (__attribute__((address_space(3))) void*)l, 16, 0, 0);
}

// Fused GEMM + epilogue job.
// C(row,col) = sum_k A1[row,k]*B1t[col,k]  (k in [0,K1))
//            + sum_k A2[row,k]*B2t[col,k]  (k in [K1,Ktot), stride K2s)
// then: += extra[row,col] (fp32) if extra else += bias[col];
//       if s_old: v = s_old + LR*(v - s_old);
//       if f32out: store fp32 raw (no clip)  [c1f mode]
//       else: clip to [0,1], store fp16 state; optional stripped fp32 finout.
struct FJob {
    const fp16_t *A1, *B1t, *A2, *B2t;
    const float  *bias;
    const float  *extra;
    const fp16_t *s_old;
    fp16_t       *outb;
    float        *f32out;
    float        *finout;
    int K1, K2s, Ktot, Ntot;
};

// ---------------------------------------------------------------------------
// Fused kernel: 64x64 output tile per block, 256 thr = 4 waves. Waves split K
// four ways (independent, barrier-free K-loops: per-wave double-buffered LDS
// staging, counted s_waitcnt vmcnt(8)), then 2-barrier LDS cross-wave
// reduction + fused epilogue. LDS exactly 64 KB -> 2 blocks/CU (8 waves/CU,
// same occupancy as the previous split-K kernel). Ntot=2048 jobs: 16bm x 32bn
// = 512 blocks = all resident. bn pinned per XCD (blk&7) -> B-panel 256 cols
// x Ktot fp16 <= 2 MB per XCD L2.
// ---------------------------------------------------------------------------
__global__ __launch_bounds__(256, 2) void gemm_fused_kernel(FJob j0, FJob j1, int nb0)
{
    // per-wave staging: [wave][buf][A|B][64 rows][32 k] fp16 = 4 KB/tile, 64 KB total
    __shared__ __align__(16) fp16_t sm[4][2][2][64][32];

    const int tid  = threadIdx.x;
    const int lane = tid & 63;
    const int w    = tid >> 6;         // wave 0..3 = K-quarter
    const int quad = lane >> 4;
    const int lrow = lane & 15;

    int bblk = blockIdx.x;
    const FJob j = (bblk < nb0) ? j0 : j1;       // block-uniform
    if (bblk >= nb0) bblk -= nb0;

    const int xcd = bblk & 7;                    // blockIdx%8 ~ XCD
    const int g   = bblk >> 3;
    const int bm  = g & 15;
    const int bn  = (j.Ntot == 2048) ? xcd * 4 + (g >> 4)    // 32 bn, 4/XCD
                                     : xcd * 2 + (g >> 4);   // 16 bn, 2/XCD

    const int KQ  = j.Ktot >> 2;       // per-wave K range (multiple of 32)
    const int kq0 = w * KQ;

    // staging: 8 cp16/wave/buf; cp16 = 16 rows x 32 fp16 (1 KB), lane ->
    // (row=lane/4, col=(lane&3)*8) matches linear LDS base + lane*16.
    const int sr  = lane >> 2;
    const int sc8 = (lane & 3) * 8;
    const fp16_t* a1 = j.A1  + (size_t)(bm * 64 + sr) * j.K1 + sc8;
    const fp16_t* b1 = j.B1t + (size_t)(bn * 64 + sr) * j.K1 + sc8;
    const fp16_t* a2 = j.A2  ? j.A2  + (size_t)(bm * 64 + sr) * j.K2s + sc8 : nullptr;
    const fp16_t* b2 = j.B2t ? j.B2t + (size_t)(bn * 64 + sr) * j.K2s + sc8 : nullptr;

    // kc is wave-uniform; K1 is a multiple of 32 so a 32-step never straddles
    // the section boundary (jL3 quarter 2 crosses K1 between steps only).
    auto stage = [&](int buf, int kc) {
        const fp16_t *as, *bs; size_t st;
        if (kc < j.K1) { as = a1 + kc;          bs = b1 + kc;          st = (size_t)16 * j.K1;  }
        else           { as = a2 + (kc - j.K1); bs = b2 + (kc - j.K1); st = (size_t)16 * j.K2s; }
        #pragma unroll
        for (int ch = 0; ch < 4; ++ch) {
            async_cp16(as + (size_t)ch * st, &sm[w][buf][0][ch * 16][0]);
            async_cp16(bs + (size_t)ch * st, &sm[w][buf][1][ch * 16][0]);
        }
    };

    v4f acc[4][4] = {};
    const int iters = KQ >> 5;         // BK = 32 per step (one MFMA K-depth)

    stage(0, kq0);
    for (int it = 0; it < iters; ++it) {
        const int cur = it & 1;
        if (it + 1 < iters) {
            // close the WAR window: my ds_reads of buf cur^1 (prev iter) must
            // retire before cp16 data can land there.
            asm volatile("s_waitcnt lgkmcnt(0)" ::: "memory");
            stage(cur ^ 1, kq0 + (it + 1) * 32);
            asm volatile("s_waitcnt vmcnt(8)" ::: "memory");   // buf cur ready, next in flight
        } else {
            asm volatile("s_waitcnt vmcnt(0)" ::: "memory");   // last tile ready
        }
        v8h af[4], bv[4];
        #pragma unroll
        for (int fm = 0; fm < 4; ++fm)
            af[fm] = *(const v8h*)&sm[w][cur][0][fm * 16 + lrow][quad * 8];
        #pragma unroll
        for (int fn = 0; fn < 4; ++fn)
            bv[fn] = *(const v8h*)&sm[w][cur][1][fn * 16 + lrow][quad * 8];
        __builtin_amdgcn_s_setprio(1);
        #pragma unroll
        for (int fm = 0; fm < 4; ++fm)
            #pragma unroll
            for (int fn = 0; fn < 4; ++fn)
                acc[fm][fn] = __builtin_amdgcn_mfma_f32_16x16x32_f16(
                    af[fm], bv[fn], acc[fm][fn], 0, 0, 0);
        __builtin_amdgcn_s_setprio(0);
    }

    // ---- cross-wave K reduction through LDS (reuse staging, 64 KB) ----
    // layout: red[wq][slot][lane] f32; slot = fm*16 + fn*4 + r. All LDS
    // accesses lane-stride-1 -> conflict-free.
    __syncthreads();                   // all waves done with staging reads
    float* red = (float*)sm;
    #pragma unroll
    for (int fm = 0; fm < 4; ++fm)
        #pragma unroll
        for (int fn = 0; fn < 4; ++fn)
            #pragma unroll
            for (int r = 0; r < 4; ++r)
                red[((w * 64 + fm * 16 + fn * 4 + r) << 6) + lane] = acc[fm][fn][r];
    __syncthreads();

    // wave w handles slots [w*16, w*16+16) -> fm == w.
    // C/D layout: col = lane&15, row = quad*4 + reg.
    const int rowbase = bm * 64 + w * 16 + quad * 4;
    const int colbase = bn * 64;
    #pragma unroll
    for (int u = 0; u < 16; ++u) {
        const int s = w * 16 + u;
        float v = red[( s        << 6) + lane]
                + red[((64  + s) << 6) + lane]
                + red[((128 + s) << 6) + lane]
                + red[((192 + s) << 6) + lane];
        const int row = rowbase + (u & 3);
        const int col = colbase + (u >> 2) * 16 + lrow;
        const size_t idx = (size_t)row * j.Ntot + col;
        if (j.extra) v += j.extra[idx];
        else         v += j.bias[col];
        if (j.s_old) {
            const float so = (float)j.s_old[idx];
            v = so + RELAX_LR * (v - so);
        }
        if (j.f32out) {
            j.f32out[idx] = v;                       // c1f mode: raw fp32, no clip
        } else {
            v = fminf(fmaxf(v, 0.f), 1.f);
            j.outb[idx] = (fp16_t)v;
            if (j.finout && col < 1000)
                j.finout[(size_t)row * 1000 + col] = v;
        }
    }
}

// fp32 W [R,C] -> fp16 Wb [Rp,Cp] (optional) + fp16 WbT [Cp,Rp], zero-padded.
__global__ void conv_w_kernel(const float* __restrict__ W, int R, int C,
                              fp16_t* Wb, fp16_t* __restrict__ WbT,
                              int Rp, int Cp)
{
    __shared__ float t[32][33];
    const int tx = threadIdx.x & 31;
    const int ty = threadIdx.x >> 5;   // 0..7
    const int r0 = blockIdx.y * 32;
    const int c0 = blockIdx.x * 32;
    #pragma unroll
    for (int i = 0; i < 4; ++i) {
        const int r = r0 + ty + i * 8;
        const int c = c0 + tx;
        float v = 0.f;
        if (r < R && c < C) v = W[(size_t)r * C + c];
        t[ty + i * 8][tx] = v;
    }
    __syncthreads();
    if (Wb) {
        #pragma unroll
        for (int i = 0; i < 4; ++i) {
            const int r = r0 + ty + i * 8;
            const int c = c0 + tx;
            if (r < Rp && c < Cp) Wb[(size_t)r * Cp + c] = (fp16_t)t[ty + i * 8][tx];
        }
    }
    #pragma unroll
    for (int i = 0; i < 4; ++i) {
        const int cc = c0 + ty + i * 8;
        const int rr = r0 + tx;
        if (cc < Cp && rr < Rp) WbT[(size_t)cc * Rp + rr] = (fp16_t)t[tx][ty + i * 8];
    }
}

__global__ void conv_x_kernel(const float* __restrict__ x,
                              fp16_t* __restrict__ xb, fp16_t* __restrict__ rxb, int n)
{
    const int i = blockIdx.x * blockDim.x + threadIdx.x;
    if (i < n) {
        const float v = x[i];
        xb[i]  = (fp16_t)v;
        rxb[i] = (fp16_t)fminf(fmaxf(v, 0.f), 1.f);
    }
}

__global__ void pad_b4_kernel(const float* __restrict__ b4, float* __restrict__ b4p)
{
    const int i = blockIdx.x * blockDim.x + threadIdx.x;
    if (i < 1024) b4p[i] = (i < 1000) ? b4[i] : 0.f;
}

extern "C" void kernel_launch(void* const* d_in, const int* in_sizes, int n_in,
                              void* d_out, int out_size, void* d_ws, size_t ws_size,
                              hipStream_t stream)
{
    const float* x  = (const float*)d_in[0];
    const float* W0 = (const float*)d_in[1];
    const float* W1 = (const float*)d_in[2];
    const float* W2 = (const float*)d_in[3];
    const float* W3 = (const float*)d_in[4];
    const float* b1 = (const float*)d_in[5];
    const float* b2 = (const float*)d_in[6];
    const float* b3 = (const float*)d_in[7];
    const float* b4 = (const float*)d_in[8];
    float* out = (float*)d_out;

    char* p = (char*)d_ws;
    auto alloc = [&](size_t bytes) {
        char* q = p;
        p += (bytes + 255) & ~(size_t)255;
        return q;
    };

    fp16_t* xb    = (fp16_t*)alloc((size_t)1024 * 2048 * 2);
    fp16_t* rxb   = (fp16_t*)alloc((size_t)1024 * 2048 * 2);
    fp16_t* Wb1   = (fp16_t*)alloc((size_t)2048 * 2048 * 2);
    fp16_t* Wb2   = (fp16_t*)alloc((size_t)2048 * 2048 * 2);
    fp16_t* Wb3   = (fp16_t*)alloc((size_t)2048 * 1024 * 2);   // padded cols
    fp16_t* WbT0  = (fp16_t*)alloc((size_t)2048 * 2048 * 2);
    fp16_t* WbT1  = (fp16_t*)alloc((size_t)2048 * 2048 * 2);
    fp16_t* WbT2  = (fp16_t*)alloc((size_t)2048 * 2048 * 2);
    fp16_t* WbT3  = (fp16_t*)alloc((size_t)1024 * 2048 * 2);   // padded rows
    fp16_t* s1b   = (fp16_t*)alloc((size_t)1024 * 2048 * 2);
    fp16_t* s2b   = (fp16_t*)alloc((size_t)1024 * 2048 * 2);
    fp16_t* s3b   = (fp16_t*)alloc((size_t)1024 * 2048 * 2);
    fp16_t* s4b   = (fp16_t*)alloc((size_t)1024 * 1024 * 2);
    float*  b4p   = (float*)alloc(1024 * 4);
    float*  c1f   = (float*)alloc((size_t)1024 * 2048 * 4);    // hoisted b1+rho(x)@W0
    (void)ws_size; (void)in_sizes; (void)n_in; (void)out_size;

    // --- setup conversions ---
    conv_x_kernel<<<(1024 * 2048 + 255) / 256, 256, 0, stream>>>(x, xb, rxb, 1024 * 2048);
    pad_b4_kernel<<<4, 256, 0, stream>>>(b4, b4p);
    conv_w_kernel<<<dim3(64, 64), 256, 0, stream>>>(W0, 2048, 2048, nullptr, WbT0, 2048, 2048);
    conv_w_kernel<<<dim3(64, 64), 256, 0, stream>>>(W1, 2048, 2048, Wb1, WbT1, 2048, 2048);
    conv_w_kernel<<<dim3(64, 64), 256, 0, stream>>>(W2, 2048, 2048, Wb2, WbT2, 2048, 2048);
    conv_w_kernel<<<dim3(32, 64), 256, 0, stream>>>(W3, 2048, 1000, Wb3, WbT3, 2048, 1024);

    const dim3 blk(256);

    // --- fused jobs: {A1,B1t,A2,B2t, bias,extra,s_old, outb,f32out,finout, K1,K2s,Ktot,Ntot}
    const FJob jC1 = { rxb, WbT0, nullptr, nullptr, b1,  nullptr, nullptr, nullptr, c1f,  nullptr, 2048, 0,    2048, 2048 };
    const FJob jI1 = { xb,  WbT0, nullptr, nullptr, b1,  nullptr, nullptr, s1b, nullptr, nullptr, 2048, 0,    2048, 2048 };
    const FJob jI2 = { s1b, WbT1, nullptr, nullptr, b2,  nullptr, nullptr, s2b, nullptr, nullptr, 2048, 0,    2048, 2048 };
    const FJob jI3 = { s2b, WbT2, nullptr, nullptr, b3,  nullptr, nullptr, s3b, nullptr, nullptr, 2048, 0,    2048, 2048 };
    const FJob jI4 = { s3b, WbT3, nullptr, nullptr, b4p, nullptr, nullptr, s4b, nullptr, nullptr, 2048, 0,    2048, 1024 };
    const FJob jL1 = { s2b, Wb1,  nullptr, nullptr, nullptr, c1f, s1b,     s1b, nullptr, nullptr, 2048, 0,    2048, 2048 };
    const FJob jL2 = { s1b, WbT1, s3b, Wb2,         b2,  nullptr, s2b,     s2b, nullptr, nullptr, 2048, 2048, 4096, 2048 };
    const FJob jL3 = { s2b, WbT2, s4b, Wb3,         b3,  nullptr, s3b,     s3b, nullptr, nullptr, 2048, 1024, 3072, 2048 };
    const FJob jL4 = { s3b, WbT3, nullptr, nullptr, b4p, nullptr, s4b,     s4b, nullptr, nullptr, 2048, 0,    2048, 1024 };
    FJob jL4f = jL4; jL4f.finout = out;

    // --- hoisted layer-1 constant: c1f = b1 + rho(x)@W0 (once, reused 25x) ---
    gemm_fused_kernel<<<512, blk, 0, stream>>>(jC1, jC1, 512);

    // --- feedforward init: s_l = clip(s_{l-1} @ W_{l-1} + b_l) ---
    gemm_fused_kernel<<<512, blk, 0, stream>>>(jI1, jI1, 512);
    gemm_fused_kernel<<<512, blk, 0, stream>>>(jI2, jI2, 512);
    gemm_fused_kernel<<<512, blk, 0, stream>>>(jI3, jI3, 512);
    gemm_fused_kernel<<<256, blk, 0, stream>>>(jI4, jI4, 256);

    // --- 25 Gauss-Seidel sweeps. Per-sweep order L1,L2,L3,L4; L4(it) and
    // L1(it+1) are independent (L4: s3->s4, L1: s2,c1f->s1) -> merged. ---
    gemm_fused_kernel<<<512, blk, 0, stream>>>(jL1, jL1, 512);           // L1, sweep 0
    for (int it = 0; it < 25; ++it) {
        gemm_fused_kernel<<<512, blk, 0, stream>>>(jL2, jL2, 512);
        gemm_fused_kernel<<<512, blk, 0, stream>>>(jL3, jL3, 512);
        if (it < 24) {
            // L4 (256 blks) first, next-sweep L1 (512 blks) backfills.
            gemm_fused_kernel<<<768, blk, 0, stream>>>(jL4, jL1, 256);
        } else {
            gemm_fused_kernel<<<256, blk, 0, stream>>>(jL4f, jL4f, 256);
        }
    }
}

// Round 2
// 2650.013 us; speedup vs baseline: 1.2175x; 1.2175x over previous
//
#include <hip/hip_runtime.h>

typedef _Float16 fp16_t;
typedef _Float16 v8h __attribute__((ext_vector_type(8)));
typedef float    v4f __attribute__((ext_vector_type(4)));

#define RELAX_LR 0.3f

// async global->LDS, 16B per lane. LDS dest = wave-uniform base + lane*16.
__device__ __forceinline__ void async_cp16(const void* g, void* l) {
    __builtin_amdgcn_global_load_lds(
        (const __attribute__((address_space(1))) void*)g,
        (__attribute__((address_space(3))) void*)l, 16, 0, 0);
}

// GEMM job: C_partial(z) = A1*B1t^T (concat K-space [0,K1)) ++ A2*B2t^T
// ([K1,K1+K2s)). Chunk z covers [z*CK,(z+1)*CK); CK is a multiple of 32 and
// K1 is a multiple of 32, so a BK=32 tile never straddles the section
// boundary (pointer select per BK-iter is block-uniform scalar work).
struct GJob {
    const fp16_t *A1, *B1t, *A2, *B2t;
    fp16_t* part;
    int K1, K2s, CK, Ntot;
};

// ---------------------------------------------------------------------------
// Split-K GEMM into fp16 partials (fp32 MFMA accumulate, one rounding at
// store). Tile BM=128 x BN=128 x BK=32, 256 thr = 4 waves, each wave 64x64
// (4x4 16x16x32 f16 MFMA). Double-buffered LDS 32 KB + launch_bounds(256,4)
// -> 4 blocks/CU (16 waves/CU): each barrier's vmcnt drain is covered by 3
// other resident blocks (r0 had 1 at 2 blocks/CU; fewer waves regressed 19%
// in the earlier session -> pushing occupancy up, not down). z=8 split fills
// the 1024-block grid at 4/CU. XCD-swizzled decode: blk%8 = XCD; z pinned
// per XCD -> per-XCD working set A(1MB)+B(2MB) < 4MB L2.
// ---------------------------------------------------------------------------
__global__ __launch_bounds__(256, 4) void gemm_splitk_kernel(GJob j0, GJob j1, int nb0)
{
    __shared__ __align__(16) fp16_t As[2][128][32];  // [stage][row][k]
    __shared__ __align__(16) fp16_t Bs[2][128][32];

    const int tid  = threadIdx.x;
    const int lane = tid & 63;
    const int w    = tid >> 6;         // wave 0..3
    const int wm   = w >> 1;           // m-half (64 rows)
    const int wn   = w & 1;            // n-half (64 cols)
    const int quad = lane >> 4;
    const int lrow = lane & 15;

    int bblk = blockIdx.x;
    const GJob j = (bblk < nb0) ? j0 : j1;       // block-uniform
    if (bblk >= nb0) bblk -= nb0;

    // swizzled decode: bblk%8 = XCD; z fixed per XCD, bn spans all columns.
    const int low3 = bblk & 7;
    const int g    = bblk >> 3;
    const int bm   = g & 7;                      // 1024/128 = 8 row tiles
    const int c    = (g >> 3) * 8 + low3;
    const int bn   = c >> 3;                     // 16 (Ntot=2048) or 8 (1024)
    const int z    = c & 7;
    const int k0   = z * j.CK;

    // staging: each cp16 = 16 rows x 32 fp16 (1 KB/wave), lane -> (row=lane/4,
    // col=(lane&3)*8) matches LDS base + lane*16. Wave w owns rows
    // [32w,32w+32) of A and B: 4 cp16/wave per stage.
    const int sr = lane >> 2;
    const int sc = (lane & 3) * 8;
    const size_t rowA = (size_t)(bm * 128 + 32 * w + sr);
    const size_t rowB = (size_t)(bn * 128 + 32 * w + sr);
    const fp16_t* a1 = j.A1  + rowA * j.K1 + sc;
    const fp16_t* b1 = j.B1t + rowB * j.K1 + sc;
    const fp16_t* a2 = j.A2  ? j.A2  + rowA * j.K2s + sc : nullptr;
    const fp16_t* b2 = j.B2t ? j.B2t + rowB * j.K2s + sc : nullptr;
    const size_t s16a = (size_t)16 * j.K1;
    const size_t s16b = (size_t)16 * j.K2s;

    auto stage = [&](int buf, int kc) {
        const fp16_t *a0, *b0; size_t st;
        if (kc < j.K1) { a0 = a1 + kc;          b0 = b1 + kc;          st = s16a; }
        else           { a0 = a2 + (kc - j.K1); b0 = b2 + (kc - j.K1); st = s16b; }
        async_cp16(a0,      &As[buf][32 * w     ][0]);
        async_cp16(a0 + st, &As[buf][32 * w + 16][0]);
        async_cp16(b0,      &Bs[buf][32 * w     ][0]);
        async_cp16(b0 + st, &Bs[buf][32 * w + 16][0]);
    };

    v4f acc[4][4] = {};
    const int iters = j.CK >> 5;       // BK = 32

    stage(0, k0);                      // prologue: tile 0 -> buffer 0

    for (int it = 0; it < iters; ++it) {
        __syncthreads();   // drains vmcnt -> buf (it&1) ready; prior ds_reads done
        if (it + 1 < iters) stage((it + 1) & 1, k0 + (it + 1) * 32);
        const int cur = it & 1;
        v8h af[4], bv[4];
        #pragma unroll
        for (int fm = 0; fm < 4; ++fm)
            af[fm] = *(const v8h*)&As[cur][wm * 64 + fm * 16 + lrow][quad * 8];
        #pragma unroll
        for (int fn = 0; fn < 4; ++fn)
            bv[fn] = *(const v8h*)&Bs[cur][wn * 64 + fn * 16 + lrow][quad * 8];
        #pragma unroll
        for (int fm = 0; fm < 4; ++fm)
            #pragma unroll
            for (int fn = 0; fn < 4; ++fn)
                acc[fm][fn] = __builtin_amdgcn_mfma_f32_16x16x32_f16(
                    af[fm], bv[fn], acc[fm][fn], 0, 0, 0);
    }

    // write fp16 partials. C/D layout: col = lane&15, row = quad*4 + reg.
    fp16_t* po = j.part + (size_t)z * 1024 * j.Ntot;
    const int rowbase = bm * 128 + wm * 64 + quad * 4;
    const int colbase = bn * 128 + wn * 64;
    #pragma unroll
    for (int fn = 0; fn < 4; ++fn) {
        const int col = colbase + fn * 16 + lrow;
        #pragma unroll
        for (int fm = 0; fm < 4; ++fm) {
            const int row = rowbase + fm * 16;
            #pragma unroll
            for (int r = 0; r < 4; ++r)
                po[(size_t)(row + r) * j.Ntot + col] = (fp16_t)acc[fm][fn][r];
        }
    }
}

// Reduce job: sum nz fp16 partial slices + (bias[col] OR per-element fp32
// extra), optional relax-update vs s_old, clip, fp16 state write; optional
// fp32 final output stripped to [1024,1000].
struct RJob {
    const fp16_t* part;
    const float* bias;
    const float* extra;
    const fp16_t* s_old;
    fp16_t* outb;
    float* finout;
    int nz, Ntot, do_update;
};

__global__ __launch_bounds__(256) void reduce_update_kernel(RJob j0, RJob j1, int nb0)
{
    int b = blockIdx.x;
    const RJob j = (b < nb0) ? j0 : j1;          // block-uniform
    if (b >= nb0) b -= nb0;
    const size_t e = ((size_t)b * 256 + threadIdx.x) * 8;  // grids sized exactly

    float v[8];
    {
        const v8h p0 = *(const v8h*)(j.part + e);
        #pragma unroll
        for (int k = 0; k < 8; ++k) v[k] = (float)p0[k];
    }
    for (int z = 1; z < j.nz; ++z) {
        const v8h p = *(const v8h*)(j.part + (size_t)z * 1024 * j.Ntot + e);
        #pragma unroll
        for (int k = 0; k < 8; ++k) v[k] += (float)p[k];
    }
    const int col = (int)e & (j.Ntot - 1);
    if (j.extra) {
        const float4 e0 = *(const float4*)(j.extra + e);
        const float4 e1 = *(const float4*)(j.extra + e + 4);
        v[0] += e0.x; v[1] += e0.y; v[2] += e0.z; v[3] += e0.w;
        v[4] += e1.x; v[5] += e1.y; v[6] += e1.z; v[7] += e1.w;
    } else {
        const float4 b0 = *(const float4*)(j.bias + col);
        const float4 b1 = *(const float4*)(j.bias + col + 4);
        v[0] += b0.x; v[1] += b0.y; v[2] += b0.z; v[3] += b0.w;
        v[4] += b1.x; v[5] += b1.y; v[6] += b1.z; v[7] += b1.w;
    }
    if (j.do_update) {
        const v8h so = *(const v8h*)(j.s_old + e);
        #pragma unroll
        for (int k = 0; k < 8; ++k) {
            const float s = (float)so[k];
            v[k] = s + RELAX_LR * (v[k] - s);
        }
    }
    #pragma unroll
    for (int k = 0; k < 8; ++k) v[k] = fminf(fmaxf(v[k], 0.f), 1.f);
    v8h h;
    #pragma unroll
    for (int k = 0; k < 8; ++k) h[k] = (fp16_t)v[k];
    *(v8h*)(j.outb + e) = h;

    if (j.finout && col < 1000) {
        const int row = (int)(e >> 10);          // Ntot == 1024 on this path
        float* o = j.finout + (size_t)row * 1000 + col;
        float4 o0 = {v[0], v[1], v[2], v[3]};
        float4 o1 = {v[4], v[5], v[6], v[7]};
        *(float4*)o       = o0;
        *(float4*)(o + 4) = o1;
    }
}

// c1f = sum of 8 fp16 partial slices + bias (fp32, no clip): the
// loop-invariant layer-1 constant b1 + rho(x)@W0, computed once.
__global__ __launch_bounds__(256) void makec1_kernel(
    const fp16_t* __restrict__ part, const float* __restrict__ bias,
    float* __restrict__ c1f, int total8)
{
    const int i = blockIdx.x * 256 + threadIdx.x;
    if (i >= total8) return;
    const size_t e = (size_t)i * 8;
    float v[8];
    {
        const v8h p0 = *(const v8h*)(part + e);
        #pragma unroll
        for (int k = 0; k < 8; ++k) v[k] = (float)p0[k];
    }
    #pragma unroll
    for (int z = 1; z < 8; ++z) {
        const v8h p = *(const v8h*)(part + (size_t)z * 1024 * 2048 + e);
        #pragma unroll
        for (int k = 0; k < 8; ++k) v[k] += (float)p[k];
    }
    const int col = (int)e & 2047;
    const float4 b0 = *(const float4*)(bias + col);
    const float4 b1 = *(const float4*)(bias + col + 4);
    v[0] += b0.x; v[1] += b0.y; v[2] += b0.z; v[3] += b0.w;
    v[4] += b1.x; v[5] += b1.y; v[6] += b1.z; v[7] += b1.w;
    float4 o0 = {v[0], v[1], v[2], v[3]};
    float4 o1 = {v[4], v[5], v[6], v[7]};
    *(float4*)(c1f + e)     = o0;
    *(float4*)(c1f + e + 4) = o1;
}

// fp32 W [R,C] -> fp16 Wb [Rp,Cp] (optional) + fp16 WbT [Cp,Rp], zero-padded.
__global__ void conv_w_kernel(const float* __restrict__ W, int R, int C,
                              fp16_t* Wb, fp16_t* __restrict__ WbT,
                              int Rp, int Cp)
{
    __shared__ float t[32][33];
    const int tx = threadIdx.x & 31;
    const int ty = threadIdx.x >> 5;   // 0..7
    const int r0 = blockIdx.y * 32;
    const int c0 = blockIdx.x * 32;
    #pragma unroll
    for (int i = 0; i < 4; ++i) {
        const int r = r0 + ty + i * 8;
        const int c = c0 + tx;
        float v = 0.f;
        if (r < R && c < C) v = W[(size_t)r * C + c];
        t[ty + i * 8][tx] = v;
    }
    __syncthreads();
    if (Wb) {
        #pragma unroll
        for (int i = 0; i < 4; ++i) {
            const int r = r0 + ty + i * 8;
            const int c = c0 + tx;
            if (r < Rp && c < Cp) Wb[(size_t)r * Cp + c] = (fp16_t)t[ty + i * 8][tx];
        }
    }
    #pragma unroll
    for (int i = 0; i < 4; ++i) {
        const int cc = c0 + ty + i * 8;
        const int rr = r0 + tx;
        if (cc < Cp && rr < Rp) WbT[(size_t)cc * Rp + rr] = (fp16_t)t[tx][ty + i * 8];
    }
}

__global__ void conv_x_kernel(const float* __restrict__ x,
                              fp16_t* __restrict__ xb, fp16_t* __restrict__ rxb, int n)
{
    const int i = blockIdx.x * blockDim.x + threadIdx.x;
    if (i < n) {
        const float v = x[i];
        xb[i]  = (fp16_t)v;
        rxb[i] = (fp16_t)fminf(fmaxf(v, 0.f), 1.f);
    }
}

__global__ void pad_b4_kernel(const float* __restrict__ b4, float* __restrict__ b4p)
{
    const int i = blockIdx.x * blockDim.x + threadIdx.x;
    if (i < 1024) b4p[i] = (i < 1000) ? b4[i] : 0.f;
}

extern "C" void kernel_launch(void* const* d_in, const int* in_sizes, int n_in,
                              void* d_out, int out_size, void* d_ws, size_t ws_size,
                              hipStream_t stream)
{
    const float* x  = (const float*)d_in[0];
    const float* W0 = (const float*)d_in[1];
    const float* W1 = (const float*)d_in[2];
    const float* W2 = (const float*)d_in[3];
    const float* W3 = (const float*)d_in[4];
    const float* b1 = (const float*)d_in[5];
    const float* b2 = (const float*)d_in[6];
    const float* b3 = (const float*)d_in[7];
    const float* b4 = (const float*)d_in[8];
    float* out = (float*)d_out;

    char* p = (char*)d_ws;
    auto alloc = [&](size_t bytes) {
        char* q = p;
        p += (bytes + 255) & ~(size_t)255;
        return q;
    };

    fp16_t* xb    = (fp16_t*)alloc((size_t)1024 * 2048 * 2);
    fp16_t* rxb   = (fp16_t*)alloc((size_t)1024 * 2048 * 2);
    fp16_t* Wb1   = (fp16_t*)alloc((size_t)2048 * 2048 * 2);
    fp16_t* Wb2   = (fp16_t*)alloc((size_t)2048 * 2048 * 2);
    fp16_t* Wb3   = (fp16_t*)alloc((size_t)2048 * 1024 * 2);   // padded cols
    fp16_t* WbT0  = (fp16_t*)alloc((size_t)2048 * 2048 * 2);
    fp16_t* WbT1  = (fp16_t*)alloc((size_t)2048 * 2048 * 2);
    fp16_t* WbT2  = (fp16_t*)alloc((size_t)2048 * 2048 * 2);
    fp16_t* WbT3  = (fp16_t*)alloc((size_t)1024 * 2048 * 2);   // padded rows
    fp16_t* s1b   = (fp16_t*)alloc((size_t)1024 * 2048 * 2);
    fp16_t* s2b   = (fp16_t*)alloc((size_t)1024 * 2048 * 2);
    fp16_t* s3b   = (fp16_t*)alloc((size_t)1024 * 2048 * 2);
    fp16_t* s4b   = (fp16_t*)alloc((size_t)1024 * 1024 * 2);
    float*  b4p   = (float*)alloc(1024 * 4);
    float*  c1f   = (float*)alloc((size_t)1024 * 2048 * 4);    // hoisted b1+rho(x)@W0
    fp16_t* partA = (fp16_t*)alloc((size_t)8 * 1024 * 1024 * 2); // 16 MB (Ntot=1024 jobs)
    fp16_t* partB = (fp16_t*)alloc((size_t)8 * 1024 * 2048 * 2); // 32 MB (Ntot=2048 jobs)
    (void)ws_size; (void)in_sizes; (void)n_in; (void)out_size;

    // --- setup conversions ---
    conv_x_kernel<<<(1024 * 2048 + 255) / 256, 256, 0, stream>>>(x, xb, rxb, 1024 * 2048);
    pad_b4_kernel<<<4, 256, 0, stream>>>(b4, b4p);
    conv_w_kernel<<<dim3(64, 64), 256, 0, stream>>>(W0, 2048, 2048, nullptr, WbT0, 2048, 2048);
    conv_w_kernel<<<dim3(64, 64), 256, 0, stream>>>(W1, 2048, 2048, Wb1, WbT1, 2048, 2048);
    conv_w_kernel<<<dim3(64, 64), 256, 0, stream>>>(W2, 2048, 2048, Wb2, WbT2, 2048, 2048);
    conv_w_kernel<<<dim3(32, 64), 256, 0, stream>>>(W3, 2048, 1000, Wb3, WbT3, 2048, 1024);

    const dim3 blk(256);
    const int rg2048 = 1024 * 2048 / 8 / 256;   // 1024 blocks
    const int rg1024 = 1024 * 1024 / 8 / 256;   // 512 blocks

    // --- GEMM jobs (A1,B1t,A2,B2t,part,K1,K2s,CK,Ntot); z=8 split always ---
    const GJob jC1 = { rxb, WbT0, nullptr, nullptr, partB, 2048, 0,    256, 2048 };
    const GJob jI1 = { xb,  WbT0, nullptr, nullptr, partB, 2048, 0,    256, 2048 };
    const GJob jI2 = { s1b, WbT1, nullptr, nullptr, partB, 2048, 0,    256, 2048 };
    const GJob jI3 = { s2b, WbT2, nullptr, nullptr, partB, 2048, 0,    256, 2048 };
    const GJob jI4 = { s3b, WbT3, nullptr, nullptr, partA, 2048, 0,    256, 1024 };
    const GJob jL1 = { s2b, Wb1,  nullptr, nullptr, partB, 2048, 0,    256, 2048 };
    const GJob jL2 = { s1b, WbT1, s3b, Wb2,         partB, 2048, 2048, 512, 2048 };
    const GJob jL3 = { s2b, WbT2, s4b, Wb3,         partB, 2048, 1024, 384, 2048 }; // 8x384, crossings on 32-step boundary
    const GJob jL4 = { s3b, WbT3, nullptr, nullptr, partA, 2048, 0,    256, 1024 };

    // --- reduce jobs (part,bias,extra,s_old,outb,finout,nz,Ntot,do_update) ---
    const RJob rI1 = { partB, b1,  nullptr, nullptr, s1b, nullptr, 8, 2048, 0 };
    const RJob rI2 = { partB, b2,  nullptr, nullptr, s2b, nullptr, 8, 2048, 0 };
    const RJob rI3 = { partB, b3,  nullptr, nullptr, s3b, nullptr, 8, 2048, 0 };
    const RJob rI4 = { partA, b4p, nullptr, nullptr, s4b, nullptr, 8, 1024, 0 };
    const RJob rL1 = { partB, nullptr, c1f, s1b, s1b, nullptr, 8, 2048, 1 };
    const RJob rL2 = { partB, b2,  nullptr, s2b, s2b, nullptr, 8, 2048, 1 };
    const RJob rL3 = { partB, b3,  nullptr, s3b, s3b, nullptr, 8, 2048, 1 };
    const RJob rL4 = { partA, b4p, nullptr, s4b, s4b, nullptr, 8, 1024, 1 };
    RJob rL4f = rL4; rL4f.finout = out;

    // --- hoisted layer-1 constant: c1f = b1 + rho(x)@W0 (once, reused 25x) ---
    gemm_splitk_kernel<<<1024, blk, 0, stream>>>(jC1, jC1, 1024);
    makec1_kernel<<<rg2048, blk, 0, stream>>>(partB, b1, c1f, 1024 * 2048 / 8);

    // --- feedforward init: s_l = clip(s_{l-1} @ W_{l-1} + b_l) ---
    gemm_splitk_kernel<<<1024, blk, 0, stream>>>(jI1, jI1, 1024);
    reduce_update_kernel<<<rg2048, blk, 0, stream>>>(rI1, rI1, rg2048);
    gemm_splitk_kernel<<<1024, blk, 0, stream>>>(jI2, jI2, 1024);
    reduce_update_kernel<<<rg2048, blk, 0, stream>>>(rI2, rI2, rg2048);
    gemm_splitk_kernel<<<1024, blk, 0, stream>>>(jI3, jI3, 1024);
    reduce_update_kernel<<<rg2048, blk, 0, stream>>>(rI3, rI3, rg2048);
    gemm_splitk_kernel<<<512, blk, 0, stream>>>(jI4, jI4, 512);
    reduce_update_kernel<<<rg1024, blk, 0, stream>>>(rI4, rI4, rg1024);

    // --- 25 Gauss-Seidel sweeps. Layer order per sweep is L1,L2,L3,L4, but
    // L4(sweep it) and L1(sweep it+1) are mutually independent (L4 reads s3,
    // L1 reads s2 + c1f) -> merged into one GEMM + one reduce dispatch. ---
    gemm_splitk_kernel<<<1024, blk, 0, stream>>>(jL1, jL1, 1024);        // L1, sweep 0
    reduce_update_kernel<<<rg2048, blk, 0, stream>>>(rL1, rL1, rg2048);
    for (int it = 0; it < 25; ++it) {
        gemm_splitk_kernel<<<1024, blk, 0, stream>>>(jL2, jL2, 1024);
        reduce_update_kernel<<<rg2048, blk, 0, stream>>>(rL2, rL2, rg2048);
        gemm_splitk_kernel<<<1024, blk, 0, stream>>>(jL3, jL3, 1024);
        reduce_update_kernel<<<rg2048, blk, 0, stream>>>(rL3, rL3, rg2048);
        if (it < 24) {
            gemm_splitk_kernel<<<1536, blk, 0, stream>>>(jL4, jL1, 512); // L4 + next L1
            reduce_update_kernel<<<rg1024 + rg2048, blk, 0, stream>>>(rL4, rL1, rg1024);
        } else {
            gemm_splitk_kernel<<<512, blk, 0, stream>>>(jL4, jL4, 512);
            reduce_update_kernel<<<rg1024, blk, 0, stream>>>(rL4f, rL4f, rg1024);
        }
    }
}